// Round 17
// baseline (146.240 us; speedup 1.0000x reference)
//
#include <hip/hip_runtime.h>
#include <hip/hip_bf16.h>

// AttentionHeadRankFour: B=8, X=8, S=1024, D_IN=512, D_OUT=64
// out = softmax_causal( (Xq Wq)(Xk Wk)^T / sqrt(S) ) (Xv Wv)
//
// Pass 0: wprep -> bf16 fragment-ordered W (q_w pre-scaled by log2e/32).
// Pass 1: proj: LDS-staged GEMM + nt A loads; V written in MFMA-fragment
//         order (r16 win: kills the [d][s] L2 channel-camped gather).
// Pass 2: attn v10 — v9 base + software pipeline: static kA/kB K-register
//         prefetch (K(c+1) in flight during PV(c)), double-buffered P in
//         LDS, explicit fences removed.

typedef short  short8 __attribute__((ext_vector_type(8)));
typedef float  f32x4  __attribute__((ext_vector_type(4)));

#define DIN   512
#define DOUT  64
#define SEQ   1024
#define NROWS 65536   // 8*8*1024

__device__ __forceinline__ unsigned short f2bf(float f) {
    unsigned int u = __float_as_uint(f);
    u += 0x7FFF + ((u >> 16) & 1);   // RNE
    return (unsigned short)(u >> 16);
}

__device__ __forceinline__ unsigned short f2bf_rhu(float f) {   // round-half-up (cheap)
    return (unsigned short)((__float_as_uint(f) + 0x8000u) >> 16);
}

__device__ __forceinline__ float fast_exp2(float x) {
    float r;
    asm("v_exp_f32 %0, %1" : "=v"(r) : "v"(x));
    return r;
}

// ---------------------------------------------------------------------------
// Weight prep: grid (16,3), 256 thr. Wfrag[mode][kk][nt][lane][8] bf16,
// element = W[kk*32 + lg*8 + j][nt*16 + lr]; mode 2 pre-scaled by log2e/32.
// ---------------------------------------------------------------------------
__global__ __launch_bounds__(256)
void wprep_kernel(const float* __restrict__ k_w, const float* __restrict__ v_w,
                  const float* __restrict__ q_w, unsigned short* __restrict__ Wfrag)
{
    const int mode = blockIdx.y;
    const float* w = (mode == 0) ? k_w : (mode == 1) ? v_w : q_w;
    const float sc = (mode == 2) ? 0.0450842200277801f : 1.0f;  // log2(e)/32
    unsigned short* outp = Wfrag + (size_t)mode * 32768;

    const int s  = blockIdx.x * 256 + threadIdx.x;   // (kk,nt,lane) slot
    const int l  = s & 63;
    const int nt = (s >> 6) & 3;
    const int kk = s >> 8;
    const int lr = l & 15, lg = l >> 4;
    short8 frag;
    #pragma unroll
    for (int j = 0; j < 8; ++j)
        frag[j] = (short)f2bf(w[(kk * 32 + lg * 8 + j) * 64 + nt * 16 + lr] * sc);
    *(short8*)&outp[(size_t)s * 8] = frag;
}

// ---------------------------------------------------------------------------
// proj. Grid (512, 3), 512 thr = 8 waves. Block: 128 rows x K=512.
// Non-temporal coalesced A loads -> f2bf -> XOR-swizzled LDS double buffer.
// mode 0: keys -> Kb [row][64]; mode 2: queries -> Qb [row][64];
// mode 1: values -> Vfrag[bx][sg][dt][lane][8] (PV fragment order).
// ---------------------------------------------------------------------------
__global__ __launch_bounds__(512, 2)
void proj_kernel(const float* __restrict__ k_in, const float* __restrict__ v_in,
                 const float* __restrict__ q_in,
                 const unsigned short* __restrict__ Wfrag,
                 unsigned short* __restrict__ Kb, unsigned short* __restrict__ Vf,
                 unsigned short* __restrict__ Qb)
{
    const int mode = blockIdx.y;
    const float* in = (mode == 0) ? k_in : (mode == 1) ? v_in : q_in;
    const unsigned short* wf = Wfrag + (size_t)mode * 32768;

    __shared__ __align__(16) unsigned short Wlds[32768];       // 64 KB
    __shared__ __align__(16) unsigned short Alds[2][16384];    // 2 x 32 KB

    const int tid = threadIdx.x;
    const int wid = tid >> 6;
    const int l   = tid & 63;
    const int lr  = l & 15;
    const int lg  = l >> 4;
    const int r0  = blockIdx.x * 128;

    const int srow = tid >> 5;
    const int scol = tid & 31;
    const float* sbase = in + (size_t)(r0 + srow) * DIN + scol * 4;

    f32x4 rA[8], rB[8];

    #define LOADC(r, c)                                                        \
        { _Pragma("unroll")                                                    \
          for (int i = 0; i < 8; ++i)                                          \
              r[i] = __builtin_nontemporal_load(                               \
                  (const f32x4*)(sbase + (size_t)i * 16 * DIN + (c) * 128)); }

    #define WRITEC(buf, r)                                                     \
        { _Pragma("unroll")                                                    \
          for (int i = 0; i < 8; ++i) {                                        \
              const int row = srow + i * 16;                                   \
              ushort4 pk;                                                      \
              pk.x = f2bf(r[i].x); pk.y = f2bf(r[i].y);                        \
              pk.z = f2bf(r[i].z); pk.w = f2bf(r[i].w);                        \
              *(ushort4*)((char*)&Alds[buf][0] +                               \
                  ((row * 256 + scol * 8) ^ ((row & 7) << 4))) = pk;           \
          } }

    const int arow  = wid * 16 + lr;
    const int abase = arow * 256 + lg * 16;     // byte offset, + kk*64
    const int aswz  = (arow & 7) << 4;

    f32x4 acc[4];
    #pragma unroll
    for (int nt = 0; nt < 4; ++nt)
        #pragma unroll
        for (int i = 0; i < 4; ++i) acc[nt][i] = 0.f;

    #define COMPUTEC(buf, c)                                                   \
        { _Pragma("unroll")                                                    \
          for (int k = 0; k < 4; ++k) {                                        \
              const short8 af = *(const short8*)((const char*)&Alds[buf][0] +  \
                                  ((abase + k * 64) ^ aswz));                  \
              const int kk = (c) * 4 + k;                                      \
              _Pragma("unroll")                                                \
              for (int nt = 0; nt < 4; ++nt) {                                 \
                  const short8 bf = *(const short8*)&Wlds[((kk * 4 + nt) * 64 + l) * 8]; \
                  acc[nt] = __builtin_amdgcn_mfma_f32_16x16x32_bf16(af, bf, acc[nt], 0, 0, 0); \
              }                                                                \
          } }

    LOADC(rA, 0);
    LOADC(rB, 1);
    #pragma unroll
    for (int i = 0; i < 8; ++i)
        *(short8*)&Wlds[(i * 512 + tid) * 8] = *(const short8*)&wf[(size_t)(i * 512 + tid) * 8];
    WRITEC(0, rA);
    __syncthreads();

    // c=0
    LOADC(rA, 2);
    WRITEC(1, rB);
    COMPUTEC(0, 0);
    __syncthreads();
    // c=1
    LOADC(rB, 3);
    WRITEC(0, rA);
    COMPUTEC(1, 1);
    __syncthreads();
    // c=2
    WRITEC(1, rB);
    COMPUTEC(0, 2);
    __syncthreads();
    // c=3
    COMPUTEC(1, 3);

    if (mode == 1) {
        // lane holds acc[nt][i] = V[grow + i][nt*16 + lr].
        // Fragment slot for (s,d): sg=s>>5, l' = (((s&31)>>3)<<4)|lr, j = s&7.
        const int grow = r0 + wid * 16 + lg * 4;
        const int bx = grow >> 10;
        const int sl = grow & 1023;
        const int sg = sl >> 5;
        const int lp = (((sl & 31) >> 3) << 4) | lr;
        const int j0 = sl & 7;
        #pragma unroll
        for (int nt = 0; nt < 4; ++nt) {
            ushort4 pk;
            pk.x = f2bf(acc[nt][0]); pk.y = f2bf(acc[nt][1]);
            pk.z = f2bf(acc[nt][2]); pk.w = f2bf(acc[nt][3]);
            *(ushort4*)&Vf[(((size_t)bx * 32 + sg) * 4 + nt) * 512 + (size_t)lp * 8 + j0] = pk;
        }
    } else {
        unsigned short* outp = (mode == 0) ? Kb : Qb;
        const int rbase = r0 + wid * 16 + lg * 4;
        #pragma unroll
        for (int nt = 0; nt < 4; ++nt)
            #pragma unroll
            for (int i = 0; i < 4; ++i)
                outp[(size_t)(rbase + i) * 64 + nt * 16 + lr] = f2bf(acc[nt][i]);
    }
    #undef LOADC
    #undef WRITEC
    #undef COMPUTEC
}

// ---------------------------------------------------------------------------
// attn v10. Grid (64 bx, 16 qblk), 256 thr = 4 waves; wave owns 16 q-rows.
// XCD locality: linear id = bx + 64*qblk => XCD = bx%8. qblk = 15 - y.
// All waves in a block run exactly qblk+1 chunks (block-uniform).
// Pipeline: K(c+1) prefetched into alternate static register set during
// PV(c); P double-buffered in LDS; no explicit fences. Fixed-m softmax
// p = 2^(s-8). PV B-operands from Vfrag (1 KB contiguous per wave instr).
// ---------------------------------------------------------------------------
__global__ __launch_bounds__(256, 3)
void attn_kernel(const unsigned short* __restrict__ Qb,
                 const unsigned short* __restrict__ Kb,
                 const unsigned short* __restrict__ Vf,
                 float* __restrict__ out)
{
    __shared__ __align__(16) unsigned short Plds[4][2][16][72];  // [wave][buf][q][key]

    const int tid  = threadIdx.x;
    const int wid  = tid >> 6;
    const int l    = tid & 63;
    const int lr   = l & 15;
    const int lg   = l >> 4;
    const int bx   = blockIdx.x;
    const int qblk = 15 - (int)blockIdx.y;       // big blocks first
    const int qw0  = qblk * 64 + wid * 16;

    const unsigned short* Qp = Qb + (size_t)bx * 65536;
    const unsigned short* Kp = Kb + (size_t)bx * 65536;
    const unsigned short* Vp = Vf + (size_t)bx * 65536;   // fragment order

    const short8 qa0 = *(const short8*)&Qp[(size_t)(qw0 + lr) * 64 + lg * 8];
    const short8 qa1 = *(const short8*)&Qp[(size_t)(qw0 + lr) * 64 + 32 + lg * 8];

    const int qrow = qw0 + lg * 4;   // + i

    float lsum[4] = {0.f, 0.f, 0.f, 0.f};
    f32x4 acc[4];
    #pragma unroll
    for (int dt = 0; dt < 4; ++dt)
        #pragma unroll
        for (int i = 0; i < 4; ++i) acc[dt][i] = 0.f;

    short8 kA[8], kB[8];

    #define LOADK(dst, kb_)                                                    \
        { _Pragma("unroll")                                                    \
          for (int kt = 0; kt < 4; ++kt) {                                     \
              dst[kt * 2]     = *(const short8*)&Kp[(size_t)((kb_) + kt * 16 + lr) * 64 + lg * 8]; \
              dst[kt * 2 + 1] = *(const short8*)&Kp[(size_t)((kb_) + kt * 16 + lr) * 64 + 32 + lg * 8]; \
          } }

    #define SCORES(src, pb, kb_)                                               \
        { _Pragma("unroll")                                                    \
          for (int kt = 0; kt < 4; ++kt) {                                     \
              const int kbase = (kb_) + kt * 16;                               \
              if (kbase <= qw0) {                                              \
                  f32x4 t;                                                     \
                  _Pragma("unroll")                                            \
                  for (int i = 0; i < 4; ++i) t[i] = 0.f;                      \
                  t = __builtin_amdgcn_mfma_f32_16x16x32_bf16(qa0, src[kt * 2],     t, 0, 0, 0); \
                  t = __builtin_amdgcn_mfma_f32_16x16x32_bf16(qa1, src[kt * 2 + 1], t, 0, 0, 0); \
                  const int kcol = kbase + lr;                                 \
                  _Pragma("unroll")                                            \
                  for (int i = 0; i < 4; ++i) {                                \
                      const float p = (kcol <= qrow + i) ? fast_exp2(t[i] - 8.0f) : 0.f; \
                      lsum[i] += p;                                            \
                      Plds[wid][pb][lg * 4 + i][kt * 16 + lr] = f2bf_rhu(p);   \
                  }                                                            \
              } else {                                                         \
                  _Pragma("unroll")                                            \
                  for (int i = 0; i < 4; ++i)                                  \
                      Plds[wid][pb][lg * 4 + i][kt * 16 + lr] = 0;             \
              }                                                                \
          } }

    #define PVSTEP(pb, kb_)                                                    \
        { _Pragma("unroll")                                                    \
          for (int c = 0; c < 2; ++c) {                                        \
              if ((kb_) + c * 32 <= qw0 + 15) {                                \
                  const short8 pa = *(const short8*)&Plds[wid][pb][lr][c * 32 + lg * 8]; \
                  const size_t vbase = ((size_t)(((kb_) >> 5) + c) * 4) * 512; \
                  _Pragma("unroll")                                            \
                  for (int dt = 0; dt < 4; ++dt) {                             \
                      const short8 vbd = *(const short8*)                      \
                          &Vp[vbase + (size_t)dt * 512 + (size_t)l * 8];       \
                      acc[dt] = __builtin_amdgcn_mfma_f32_16x16x32_bf16(pa, vbd, acc[dt], 0, 0, 0); \
                  }                                                            \
              }                                                                \
          } }

    const int nchunks = qblk + 1;     // block-uniform
    int kb = 0, c = 0;
    LOADK(kA, 0);
    while (true) {
        // even chunk: registers kA, P buffer 0
        SCORES(kA, 0, kb);
        if (c + 1 < nchunks) LOADK(kB, kb + 64);
        PVSTEP(0, kb);
        if (c + 1 >= nchunks) break;
        kb += 64; ++c;

        // odd chunk: registers kB, P buffer 1
        SCORES(kB, 1, kb);
        if (c + 1 < nchunks) LOADK(kA, kb + 64);
        PVSTEP(1, kb);
        if (c + 1 >= nchunks) break;
        kb += 64; ++c;
    }
    #undef LOADK
    #undef SCORES
    #undef PVSTEP

    // ---- epilogue: reduce lsum over the 16 key-lanes, normalize, store ----
    #pragma unroll
    for (int d = 1; d < 16; d <<= 1)
        #pragma unroll
        for (int i = 0; i < 4; ++i) lsum[i] += __shfl_xor(lsum[i], d);

    float inv[4];
    #pragma unroll
    for (int i = 0; i < 4; ++i) inv[i] = 1.0f / lsum[i];

    const size_t orow = (size_t)bx * 1024 + qw0;
    #pragma unroll
    for (int dt = 0; dt < 4; ++dt)
        #pragma unroll
        for (int i = 0; i < 4; ++i)
            out[(orow + lg * 4 + i) * 64 + dt * 16 + lr] = acc[dt][i] * inv[i];
}

extern "C" void kernel_launch(void* const* d_in, const int* in_sizes, int n_in,
                              void* d_out, int out_size, void* d_ws, size_t ws_size,
                              hipStream_t stream) {
    const float* k_in = (const float*)d_in[0];
    const float* v_in = (const float*)d_in[1];
    const float* q_in = (const float*)d_in[2];
    const float* k_w  = (const float*)d_in[3];
    const float* v_w  = (const float*)d_in[4];
    const float* q_w  = (const float*)d_in[5];

    unsigned short* Kb    = (unsigned short*)d_ws;              // [65536][64] bf16
    unsigned short* Vf    = Kb + (size_t)NROWS * 64;            // V fragments, 8 MB
    unsigned short* Qb    = Vf + (size_t)NROWS * 64;            // [65536][64] bf16 (scale in W)
    unsigned short* Wfrag = Qb + (size_t)NROWS * 64;            // 3 x 32768 bf16 fragments

    wprep_kernel<<<dim3(16, 3), 256, 0, stream>>>(k_w, v_w, q_w, Wfrag);
    proj_kernel<<<dim3(512, 3), 512, 0, stream>>>(
        k_in, v_in, q_in, Wfrag, Kb, Vf, Qb);
    attn_kernel<<<dim3(64, 16), 256, 0, stream>>>(Qb, Kb, Vf, (float*)d_out);
}

// Round 18
// 132.872 us; speedup vs baseline: 1.1006x; 1.1006x over previous
//
#include <hip/hip_runtime.h>
#include <hip/hip_bf16.h>

// AttentionHeadRankFour: B=8, X=8, S=1024, D_IN=512, D_OUT=64
// out = softmax_causal( (Xq Wq)(Xk Wk)^T / sqrt(S) ) (Xv Wv)
//
// Pass 0: wprep -> bf16 fragment-ordered W (q_w pre-scaled by log2e/32).
// Pass 1: proj (frozen r16): LDS-staged GEMM + nt A loads; V in MFMA-fragment
//         order (kills the [d][s] L2 channel-camped gather).
// Pass 2: attn v11 — v9 chunk shape (KVBLK=64, mfma(Q,K), fixed-m exp2,
//         Vfrag loads, XCD grid) + 2-way key split: 8 waves = 4 q-groups x
//         2 interleaved key-halves; halves combine via one LDS add
//         (fixed m => partials addable). Serial chain 16 -> 8 chunks,
//         waves 4096 -> 8192.

typedef short  short8 __attribute__((ext_vector_type(8)));
typedef float  f32x4  __attribute__((ext_vector_type(4)));

#define DIN   512
#define DOUT  64
#define SEQ   1024
#define NROWS 65536   // 8*8*1024

__device__ __forceinline__ unsigned short f2bf(float f) {
    unsigned int u = __float_as_uint(f);
    u += 0x7FFF + ((u >> 16) & 1);   // RNE
    return (unsigned short)(u >> 16);
}

__device__ __forceinline__ unsigned short f2bf_rhu(float f) {   // round-half-up (cheap)
    return (unsigned short)((__float_as_uint(f) + 0x8000u) >> 16);
}

__device__ __forceinline__ float fast_exp2(float x) {
    float r;
    asm("v_exp_f32 %0, %1" : "=v"(r) : "v"(x));
    return r;
}

// ---------------------------------------------------------------------------
// Weight prep: grid (16,3), 256 thr. Wfrag[mode][kk][nt][lane][8] bf16,
// element = W[kk*32 + lg*8 + j][nt*16 + lr]; mode 2 pre-scaled by log2e/32.
// ---------------------------------------------------------------------------
__global__ __launch_bounds__(256)
void wprep_kernel(const float* __restrict__ k_w, const float* __restrict__ v_w,
                  const float* __restrict__ q_w, unsigned short* __restrict__ Wfrag)
{
    const int mode = blockIdx.y;
    const float* w = (mode == 0) ? k_w : (mode == 1) ? v_w : q_w;
    const float sc = (mode == 2) ? 0.0450842200277801f : 1.0f;  // log2(e)/32
    unsigned short* outp = Wfrag + (size_t)mode * 32768;

    const int s  = blockIdx.x * 256 + threadIdx.x;   // (kk,nt,lane) slot
    const int l  = s & 63;
    const int nt = (s >> 6) & 3;
    const int kk = s >> 8;
    const int lr = l & 15, lg = l >> 4;
    short8 frag;
    #pragma unroll
    for (int j = 0; j < 8; ++j)
        frag[j] = (short)f2bf(w[(kk * 32 + lg * 8 + j) * 64 + nt * 16 + lr] * sc);
    *(short8*)&outp[(size_t)s * 8] = frag;
}

// ---------------------------------------------------------------------------
// proj (frozen r16). Grid (512, 3), 512 thr = 8 waves. Block: 128 rows x K=512.
// Non-temporal coalesced A loads -> f2bf -> XOR-swizzled LDS double buffer.
// mode 0: keys -> Kb [row][64]; mode 2: queries -> Qb [row][64];
// mode 1: values -> Vfrag[bx][sg][dt][lane][8] (PV fragment order).
// ---------------------------------------------------------------------------
__global__ __launch_bounds__(512, 2)
void proj_kernel(const float* __restrict__ k_in, const float* __restrict__ v_in,
                 const float* __restrict__ q_in,
                 const unsigned short* __restrict__ Wfrag,
                 unsigned short* __restrict__ Kb, unsigned short* __restrict__ Vf,
                 unsigned short* __restrict__ Qb)
{
    const int mode = blockIdx.y;
    const float* in = (mode == 0) ? k_in : (mode == 1) ? v_in : q_in;
    const unsigned short* wf = Wfrag + (size_t)mode * 32768;

    __shared__ __align__(16) unsigned short Wlds[32768];       // 64 KB
    __shared__ __align__(16) unsigned short Alds[2][16384];    // 2 x 32 KB

    const int tid = threadIdx.x;
    const int wid = tid >> 6;
    const int l   = tid & 63;
    const int lr  = l & 15;
    const int lg  = l >> 4;
    const int r0  = blockIdx.x * 128;

    const int srow = tid >> 5;
    const int scol = tid & 31;
    const float* sbase = in + (size_t)(r0 + srow) * DIN + scol * 4;

    f32x4 rA[8], rB[8];

    #define LOADC(r, c)                                                        \
        { _Pragma("unroll")                                                    \
          for (int i = 0; i < 8; ++i)                                          \
              r[i] = __builtin_nontemporal_load(                               \
                  (const f32x4*)(sbase + (size_t)i * 16 * DIN + (c) * 128)); }

    #define WRITEC(buf, r)                                                     \
        { _Pragma("unroll")                                                    \
          for (int i = 0; i < 8; ++i) {                                        \
              const int row = srow + i * 16;                                   \
              ushort4 pk;                                                      \
              pk.x = f2bf(r[i].x); pk.y = f2bf(r[i].y);                        \
              pk.z = f2bf(r[i].z); pk.w = f2bf(r[i].w);                        \
              *(ushort4*)((char*)&Alds[buf][0] +                               \
                  ((row * 256 + scol * 8) ^ ((row & 7) << 4))) = pk;           \
          } }

    const int arow  = wid * 16 + lr;
    const int abase = arow * 256 + lg * 16;     // byte offset, + kk*64
    const int aswz  = (arow & 7) << 4;

    f32x4 acc[4];
    #pragma unroll
    for (int nt = 0; nt < 4; ++nt)
        #pragma unroll
        for (int i = 0; i < 4; ++i) acc[nt][i] = 0.f;

    #define COMPUTEC(buf, c)                                                   \
        { _Pragma("unroll")                                                    \
          for (int k = 0; k < 4; ++k) {                                        \
              const short8 af = *(const short8*)((const char*)&Alds[buf][0] +  \
                                  ((abase + k * 64) ^ aswz));                  \
              const int kk = (c) * 4 + k;                                      \
              _Pragma("unroll")                                                \
              for (int nt = 0; nt < 4; ++nt) {                                 \
                  const short8 bf = *(const short8*)&Wlds[((kk * 4 + nt) * 64 + l) * 8]; \
                  acc[nt] = __builtin_amdgcn_mfma_f32_16x16x32_bf16(af, bf, acc[nt], 0, 0, 0); \
              }                                                                \
          } }

    LOADC(rA, 0);
    LOADC(rB, 1);
    #pragma unroll
    for (int i = 0; i < 8; ++i)
        *(short8*)&Wlds[(i * 512 + tid) * 8] = *(const short8*)&wf[(size_t)(i * 512 + tid) * 8];
    WRITEC(0, rA);
    __syncthreads();

    // c=0
    LOADC(rA, 2);
    WRITEC(1, rB);
    COMPUTEC(0, 0);
    __syncthreads();
    // c=1
    LOADC(rB, 3);
    WRITEC(0, rA);
    COMPUTEC(1, 1);
    __syncthreads();
    // c=2
    WRITEC(1, rB);
    COMPUTEC(0, 2);
    __syncthreads();
    // c=3
    COMPUTEC(1, 3);

    if (mode == 1) {
        // lane holds acc[nt][i] = V[grow + i][nt*16 + lr].
        // Fragment slot for (s,d): sg=s>>5, l' = (((s&31)>>3)<<4)|lr, j = s&7.
        const int grow = r0 + wid * 16 + lg * 4;
        const int bx = grow >> 10;
        const int sl = grow & 1023;
        const int sg = sl >> 5;
        const int lp = (((sl & 31) >> 3) << 4) | lr;
        const int j0 = sl & 7;
        #pragma unroll
        for (int nt = 0; nt < 4; ++nt) {
            ushort4 pk;
            pk.x = f2bf(acc[nt][0]); pk.y = f2bf(acc[nt][1]);
            pk.z = f2bf(acc[nt][2]); pk.w = f2bf(acc[nt][3]);
            *(ushort4*)&Vf[(((size_t)bx * 32 + sg) * 4 + nt) * 512 + (size_t)lp * 8 + j0] = pk;
        }
    } else {
        unsigned short* outp = (mode == 0) ? Kb : Qb;
        const int rbase = r0 + wid * 16 + lg * 4;
        #pragma unroll
        for (int nt = 0; nt < 4; ++nt)
            #pragma unroll
            for (int i = 0; i < 4; ++i)
                outp[(size_t)(rbase + i) * 64 + nt * 16 + lr] = f2bf(acc[nt][i]);
    }
    #undef LOADC
    #undef WRITEC
    #undef COMPUTEC
}

// ---------------------------------------------------------------------------
// attn v11. Grid (64 bx, 16 qblk), 512 thr = 8 waves: wave = (half, g).
// g = q-group (16 rows at qw0 = qblk*64 + g*16); half = interleaved key-half
// (kb = half*64, step 128). XCD locality: linear id = bx + 64*qblk => XCD =
// bx%8; qblk = 15-y => longest blocks first.
// Chunk (v9-proven): KVBLK=64, t = mfma(Q,K) (C: col=lr=key, row=lg*4+i=q),
// fixed-m softmax p = 2^(s-8), lane-local lsum[4]; PV B-operands from Vfrag
// (1 KB contiguous per wave instruction). Halves combine via LDS add.
// ---------------------------------------------------------------------------
__global__ __launch_bounds__(512)
void attn_kernel(const unsigned short* __restrict__ Qb,
                 const unsigned short* __restrict__ Kb,
                 const unsigned short* __restrict__ Vf,
                 float* __restrict__ out)
{
    __shared__ __align__(16) unsigned short Plds[8][16][72];   // per-wave P tile
    __shared__ __align__(16) f32x4 RedAcc[4][64][4];           // [g][lane][dt] 16 KB
    __shared__ float RedSum[4][64][4];                         // [g][lane][i]  4 KB

    const int tid  = threadIdx.x;
    const int wid  = tid >> 6;
    const int g    = wid & 3;
    const int half = wid >> 2;
    const int l    = tid & 63;
    const int lr   = l & 15;
    const int lg   = l >> 4;
    const int bx   = blockIdx.x;
    const int qblk = 15 - (int)blockIdx.y;       // big blocks first
    const int qw0  = qblk * 64 + g * 16;

    const unsigned short* Qp = Qb + (size_t)bx * 65536;
    const unsigned short* Kp = Kb + (size_t)bx * 65536;
    const unsigned short* Vp = Vf + (size_t)bx * 65536;   // fragment order

    const short8 qa0 = *(const short8*)&Qp[(size_t)(qw0 + lr) * 64 + lg * 8];
    const short8 qa1 = *(const short8*)&Qp[(size_t)(qw0 + lr) * 64 + 32 + lg * 8];

    const int qrow = qw0 + lg * 4;   // + i

    float lsum[4] = {0.f, 0.f, 0.f, 0.f};
    f32x4 acc[4];
    #pragma unroll
    for (int dt = 0; dt < 4; ++dt)
        #pragma unroll
        for (int i = 0; i < 4; ++i) acc[dt][i] = 0.f;

    for (int kb = half * 64; kb <= qw0; kb += 128) {
        // ---- scores -> p -> LDS: 4 tiles of 16 keys ----
        #pragma unroll
        for (int kt = 0; kt < 4; ++kt) {
            const int kbase = kb + kt * 16;
            if (kbase <= qw0) {                // wave-uniform (both mult of 16)
                const short8 k0 = *(const short8*)&Kp[(size_t)(kbase + lr) * 64 + lg * 8];
                const short8 k1 = *(const short8*)&Kp[(size_t)(kbase + lr) * 64 + 32 + lg * 8];
                f32x4 t;
                #pragma unroll
                for (int i = 0; i < 4; ++i) t[i] = 0.f;
                t = __builtin_amdgcn_mfma_f32_16x16x32_bf16(qa0, k0, t, 0, 0, 0);
                t = __builtin_amdgcn_mfma_f32_16x16x32_bf16(qa1, k1, t, 0, 0, 0);
                const int kcol = kbase + lr;
                #pragma unroll
                for (int i = 0; i < 4; ++i) {
                    const float p = (kcol <= qrow + i) ? fast_exp2(t[i] - 8.0f) : 0.f;
                    lsum[i] += p;
                    Plds[wid][lg * 4 + i][kt * 16 + lr] = f2bf_rhu(p);
                }
            } else {
                #pragma unroll
                for (int i = 0; i < 4; ++i)
                    Plds[wid][lg * 4 + i][kt * 16 + lr] = 0;
            }
        }

        // wave-private LDS write -> read (same wave)
        asm volatile("s_waitcnt lgkmcnt(0)" ::: "memory");
        __builtin_amdgcn_sched_barrier(0);

        // ---- PV: static 2 groups of 32 keys, fragment-ordered V loads ----
        #pragma unroll
        for (int c = 0; c < 2; ++c) {
            if (kb + c * 32 <= qw0 + 15) {     // wave-uniform
                const short8 pa = *(const short8*)&Plds[wid][lr][c * 32 + lg * 8];
                const size_t vbase = ((size_t)((kb >> 5) + c) * 4) * 512;
                #pragma unroll
                for (int dt = 0; dt < 4; ++dt) {
                    const short8 vbd = *(const short8*)
                        &Vp[vbase + (size_t)dt * 512 + (size_t)l * 8];
                    acc[dt] = __builtin_amdgcn_mfma_f32_16x16x32_bf16(pa, vbd, acc[dt], 0, 0, 0);
                }
            }
        }
        asm volatile("s_waitcnt lgkmcnt(0)" ::: "memory");
    }

    // ---- combine halves (fixed m => partials add directly) ----
    if (half == 1) {
        #pragma unroll
        for (int dt = 0; dt < 4; ++dt) RedAcc[g][l][dt] = acc[dt];
        #pragma unroll
        for (int i = 0; i < 4; ++i) RedSum[g][l][i] = lsum[i];
    }
    __syncthreads();
    if (half == 0) {
        #pragma unroll
        for (int dt = 0; dt < 4; ++dt) acc[dt] += RedAcc[g][l][dt];
        #pragma unroll
        for (int i = 0; i < 4; ++i) lsum[i] += RedSum[g][l][i];

        // reduce lsum over the 16 key-lanes (within the lg group)
        #pragma unroll
        for (int d = 1; d < 16; d <<= 1)
            #pragma unroll
            for (int i = 0; i < 4; ++i) lsum[i] += __shfl_xor(lsum[i], d);

        float inv[4];
        #pragma unroll
        for (int i = 0; i < 4; ++i) inv[i] = 1.0f / lsum[i];

        const size_t orow = (size_t)bx * 1024 + qw0;
        #pragma unroll
        for (int dt = 0; dt < 4; ++dt)
            #pragma unroll
            for (int i = 0; i < 4; ++i)
                out[(orow + lg * 4 + i) * 64 + dt * 16 + lr] = acc[dt][i] * inv[i];
    }
}

extern "C" void kernel_launch(void* const* d_in, const int* in_sizes, int n_in,
                              void* d_out, int out_size, void* d_ws, size_t ws_size,
                              hipStream_t stream) {
    const float* k_in = (const float*)d_in[0];
    const float* v_in = (const float*)d_in[1];
    const float* q_in = (const float*)d_in[2];
    const float* k_w  = (const float*)d_in[3];
    const float* v_w  = (const float*)d_in[4];
    const float* q_w  = (const float*)d_in[5];

    unsigned short* Kb    = (unsigned short*)d_ws;              // [65536][64] bf16
    unsigned short* Vf    = Kb + (size_t)NROWS * 64;            // V fragments, 8 MB
    unsigned short* Qb    = Vf + (size_t)NROWS * 64;            // [65536][64] bf16 (scale in W)
    unsigned short* Wfrag = Qb + (size_t)NROWS * 64;            // 3 x 32768 bf16 fragments

    wprep_kernel<<<dim3(16, 3), 256, 0, stream>>>(k_w, v_w, q_w, Wfrag);
    proj_kernel<<<dim3(512, 3), 512, 0, stream>>>(
        k_in, v_in, q_in, Wfrag, Kb, Vf, Qb);
    attn_kernel<<<dim3(64, 16), 512, 0, stream>>>(Qb, Kb, Vf, (float*)d_out);
}

// Round 19
// 128.537 us; speedup vs baseline: 1.1377x; 1.0337x over previous
//
#include <hip/hip_runtime.h>
#include <hip/hip_bf16.h>

// AttentionHeadRankFour: B=8, X=8, S=1024, D_IN=512, D_OUT=64
// out = softmax_causal( (Xq Wq)(Xk Wk)^T / sqrt(S) ) (Xv Wv)
//
// Pass 0: wprep -> bf16 fragment-ordered W (q_w pre-scaled by log2e/32).
// Pass 1: proj v8 — wave-private A staging (16 rows x K=512 per wave, own
//         8 KB LDS dbuf slice), nt loads, XOR swizzle; ZERO barriers in the
//         K-loop (only one after W staging) => no vmcnt(0) drains.
// Pass 2: attn v11 (frozen r18): KVBLK=64 chunks, mfma(Q,K), fixed-m exp2
//         softmax, Vfrag PV loads, XCD grid, 2-way key split.

typedef short  short8 __attribute__((ext_vector_type(8)));
typedef float  f32x4  __attribute__((ext_vector_type(4)));

#define DIN   512
#define DOUT  64
#define SEQ   1024
#define NROWS 65536   // 8*8*1024

__device__ __forceinline__ unsigned short f2bf(float f) {
    unsigned int u = __float_as_uint(f);
    u += 0x7FFF + ((u >> 16) & 1);   // RNE
    return (unsigned short)(u >> 16);
}

__device__ __forceinline__ unsigned short f2bf_rhu(float f) {   // round-half-up (cheap)
    return (unsigned short)((__float_as_uint(f) + 0x8000u) >> 16);
}

__device__ __forceinline__ float fast_exp2(float x) {
    float r;
    asm("v_exp_f32 %0, %1" : "=v"(r) : "v"(x));
    return r;
}

// ---------------------------------------------------------------------------
// Weight prep: grid (16,3), 256 thr. Wfrag[mode][kk][nt][lane][8] bf16,
// element = W[kk*32 + lg*8 + j][nt*16 + lr]; mode 2 pre-scaled by log2e/32.
// ---------------------------------------------------------------------------
__global__ __launch_bounds__(256)
void wprep_kernel(const float* __restrict__ k_w, const float* __restrict__ v_w,
                  const float* __restrict__ q_w, unsigned short* __restrict__ Wfrag)
{
    const int mode = blockIdx.y;
    const float* w = (mode == 0) ? k_w : (mode == 1) ? v_w : q_w;
    const float sc = (mode == 2) ? 0.0450842200277801f : 1.0f;  // log2(e)/32
    unsigned short* outp = Wfrag + (size_t)mode * 32768;

    const int s  = blockIdx.x * 256 + threadIdx.x;   // (kk,nt,lane) slot
    const int l  = s & 63;
    const int nt = (s >> 6) & 3;
    const int kk = s >> 8;
    const int lr = l & 15, lg = l >> 4;
    short8 frag;
    #pragma unroll
    for (int j = 0; j < 8; ++j)
        frag[j] = (short)f2bf(w[(kk * 32 + lg * 8 + j) * 64 + nt * 16 + lr] * sc);
    *(short8*)&outp[(size_t)s * 8] = frag;
}

// ---------------------------------------------------------------------------
// proj v8. Grid (512, 3), 512 thr = 8 waves. Wave owns 16 rows x K=512.
// A staged per 128-col chunk into the wave's OWN LDS slice (2 x 4 KB dbuf):
// nt loads (2 rows x 512 B contiguous per instr), f2bf, XOR-swizzled write.
// No __syncthreads in the K-loop (W-stage barrier only) -> prefetch loads
// stay in flight across chunk boundaries (per-wave vmcnt waits only).
// mode 0: keys -> Kb [row][64]; mode 2: queries -> Qb [row][64];
// mode 1: values -> Vfrag[bx][sg][dt][lane][8] (PV fragment order).
// ---------------------------------------------------------------------------
__global__ __launch_bounds__(512, 2)
void proj_kernel(const float* __restrict__ k_in, const float* __restrict__ v_in,
                 const float* __restrict__ q_in,
                 const unsigned short* __restrict__ Wfrag,
                 unsigned short* __restrict__ Kb, unsigned short* __restrict__ Vf,
                 unsigned short* __restrict__ Qb)
{
    const int mode = blockIdx.y;
    const float* in = (mode == 0) ? k_in : (mode == 1) ? v_in : q_in;
    const unsigned short* wf = Wfrag + (size_t)mode * 32768;

    __shared__ __align__(16) unsigned short Wlds[32768];        // 64 KB
    __shared__ __align__(16) unsigned short Alds[8][2][2048];   // 8 waves x 2 x 4 KB

    const int tid = threadIdx.x;
    const int wid = tid >> 6;
    const int l   = tid & 63;
    const int lr  = l & 15;
    const int lg  = l >> 4;
    const int r0  = blockIdx.x * 128 + wid * 16;   // wave's first row

    // Staging geometry (per wave): instr i covers rows 2i+(l>>5), col (l&31)*4.
    const int srow = l >> 5;            // + 2*i
    const int scolb = (l & 31) * 8;     // bf16 byte offset within row
    const float* sbase = in + (size_t)(r0 + srow) * DIN + (l & 31) * 4;

    f32x4 rA[8], rB[8];

    #define LOADC(r, c)                                                        \
        { _Pragma("unroll")                                                    \
          for (int i = 0; i < 8; ++i)                                          \
              r[i] = __builtin_nontemporal_load(                               \
                  (const f32x4*)(sbase + (size_t)(2 * i) * DIN + (c) * 128)); }

    #define WRITEC(buf, r)                                                     \
        { _Pragma("unroll")                                                    \
          for (int i = 0; i < 8; ++i) {                                        \
              const int row = 2 * i + srow;                                    \
              ushort4 pk;                                                      \
              pk.x = f2bf(r[i].x); pk.y = f2bf(r[i].y);                        \
              pk.z = f2bf(r[i].z); pk.w = f2bf(r[i].w);                        \
              *(ushort4*)((char*)&Alds[wid][buf][0] +                          \
                  ((row * 256 + scolb) ^ ((row & 7) << 4))) = pk;              \
          } }

    const int abase = lr * 256 + lg * 16;   // byte offset, + k*64
    const int aswz  = (lr & 7) << 4;

    f32x4 acc[4];
    #pragma unroll
    for (int nt = 0; nt < 4; ++nt)
        #pragma unroll
        for (int i = 0; i < 4; ++i) acc[nt][i] = 0.f;

    #define COMPUTEC(buf, c)                                                   \
        { _Pragma("unroll")                                                    \
          for (int k = 0; k < 4; ++k) {                                        \
              const short8 af = *(const short8*)((const char*)&Alds[wid][buf][0] + \
                                  ((abase + k * 64) ^ aswz));                  \
              const int kk = (c) * 4 + k;                                      \
              _Pragma("unroll")                                                \
              for (int nt = 0; nt < 4; ++nt) {                                 \
                  const short8 bf = *(const short8*)&Wlds[((kk * 4 + nt) * 64 + l) * 8]; \
                  acc[nt] = __builtin_amdgcn_mfma_f32_16x16x32_bf16(af, bf, acc[nt], 0, 0, 0); \
              }                                                                \
          } }

    // Prologue: chunk 0/1 loads in flight, then W staging + the ONLY barrier.
    LOADC(rA, 0);
    LOADC(rB, 1);
    #pragma unroll
    for (int i = 0; i < 8; ++i)
        *(short8*)&Wlds[(i * 512 + tid) * 8] = *(const short8*)&wf[(size_t)(i * 512 + tid) * 8];
    __syncthreads();

    // Barrier-free K-loop (wave-private dbuf; per-wave DS pipe is in-order).
    WRITEC(0, rA);
    LOADC(rA, 2);
    COMPUTEC(0, 0);

    WRITEC(1, rB);
    LOADC(rB, 3);
    COMPUTEC(1, 1);

    WRITEC(0, rA);
    COMPUTEC(0, 2);

    WRITEC(1, rB);
    COMPUTEC(1, 3);

    // Epilogue. C frag: col = lr, row = lg*4 + i within the wave's 16 rows.
    if (mode == 1) {
        // lane holds acc[nt][i] = V[grow + i][nt*16 + lr].
        // Fragment slot for (s,d): sg=s>>5, l' = (((s&31)>>3)<<4)|lr, j = s&7.
        const int grow = r0 + lg * 4;
        const int bx = grow >> 10;
        const int sl = grow & 1023;
        const int sg = sl >> 5;
        const int lp = (((sl & 31) >> 3) << 4) | lr;
        const int j0 = sl & 7;
        #pragma unroll
        for (int nt = 0; nt < 4; ++nt) {
            ushort4 pk;
            pk.x = f2bf(acc[nt][0]); pk.y = f2bf(acc[nt][1]);
            pk.z = f2bf(acc[nt][2]); pk.w = f2bf(acc[nt][3]);
            *(ushort4*)&Vf[(((size_t)bx * 32 + sg) * 4 + nt) * 512 + (size_t)lp * 8 + j0] = pk;
        }
    } else {
        unsigned short* outp = (mode == 0) ? Kb : Qb;
        const int rbase = r0 + lg * 4;
        #pragma unroll
        for (int nt = 0; nt < 4; ++nt)
            #pragma unroll
            for (int i = 0; i < 4; ++i)
                outp[(size_t)(rbase + i) * 64 + nt * 16 + lr] = f2bf(acc[nt][i]);
    }
    #undef LOADC
    #undef WRITEC
    #undef COMPUTEC
}

// ---------------------------------------------------------------------------
// attn v11 (frozen r18). Grid (64 bx, 16 qblk), 512 thr = 8 waves:
// wave = (half, g); g = q-group (16 rows at qw0 = qblk*64 + g*16); half =
// interleaved key-half (kb = half*64, step 128). XCD: linear id = bx+64*qblk
// => XCD = bx%8. Chunk: KVBLK=64, mfma(Q,K), fixed-m softmax p = 2^(s-8),
// Vfrag PV loads. Halves combine via LDS add (fixed m => addable).
// ---------------------------------------------------------------------------
__global__ __launch_bounds__(512)
void attn_kernel(const unsigned short* __restrict__ Qb,
                 const unsigned short* __restrict__ Kb,
                 const unsigned short* __restrict__ Vf,
                 float* __restrict__ out)
{
    __shared__ __align__(16) unsigned short Plds[8][16][72];   // per-wave P tile
    __shared__ __align__(16) f32x4 RedAcc[4][64][4];           // [g][lane][dt] 16 KB
    __shared__ float RedSum[4][64][4];                         // [g][lane][i]  4 KB

    const int tid  = threadIdx.x;
    const int wid  = tid >> 6;
    const int g    = wid & 3;
    const int half = wid >> 2;
    const int l    = tid & 63;
    const int lr   = l & 15;
    const int lg   = l >> 4;
    const int bx   = blockIdx.x;
    const int qblk = 15 - (int)blockIdx.y;       // big blocks first
    const int qw0  = qblk * 64 + g * 16;

    const unsigned short* Qp = Qb + (size_t)bx * 65536;
    const unsigned short* Kp = Kb + (size_t)bx * 65536;
    const unsigned short* Vp = Vf + (size_t)bx * 65536;   // fragment order

    const short8 qa0 = *(const short8*)&Qp[(size_t)(qw0 + lr) * 64 + lg * 8];
    const short8 qa1 = *(const short8*)&Qp[(size_t)(qw0 + lr) * 64 + 32 + lg * 8];

    const int qrow = qw0 + lg * 4;   // + i

    float lsum[4] = {0.f, 0.f, 0.f, 0.f};
    f32x4 acc[4];
    #pragma unroll
    for (int dt = 0; dt < 4; ++dt)
        #pragma unroll
        for (int i = 0; i < 4; ++i) acc[dt][i] = 0.f;

    for (int kb = half * 64; kb <= qw0; kb += 128) {
        // ---- scores -> p -> LDS: 4 tiles of 16 keys ----
        #pragma unroll
        for (int kt = 0; kt < 4; ++kt) {
            const int kbase = kb + kt * 16;
            if (kbase <= qw0) {                // wave-uniform (both mult of 16)
                const short8 k0 = *(const short8*)&Kp[(size_t)(kbase + lr) * 64 + lg * 8];
                const short8 k1 = *(const short8*)&Kp[(size_t)(kbase + lr) * 64 + 32 + lg * 8];
                f32x4 t;
                #pragma unroll
                for (int i = 0; i < 4; ++i) t[i] = 0.f;
                t = __builtin_amdgcn_mfma_f32_16x16x32_bf16(qa0, k0, t, 0, 0, 0);
                t = __builtin_amdgcn_mfma_f32_16x16x32_bf16(qa1, k1, t, 0, 0, 0);
                const int kcol = kbase + lr;
                #pragma unroll
                for (int i = 0; i < 4; ++i) {
                    const float p = (kcol <= qrow + i) ? fast_exp2(t[i] - 8.0f) : 0.f;
                    lsum[i] += p;
                    Plds[wid][lg * 4 + i][kt * 16 + lr] = f2bf_rhu(p);
                }
            } else {
                #pragma unroll
                for (int i = 0; i < 4; ++i)
                    Plds[wid][lg * 4 + i][kt * 16 + lr] = 0;
            }
        }

        // wave-private LDS write -> read (same wave)
        asm volatile("s_waitcnt lgkmcnt(0)" ::: "memory");
        __builtin_amdgcn_sched_barrier(0);

        // ---- PV: static 2 groups of 32 keys, fragment-ordered V loads ----
        #pragma unroll
        for (int c = 0; c < 2; ++c) {
            if (kb + c * 32 <= qw0 + 15) {     // wave-uniform
                const short8 pa = *(const short8*)&Plds[wid][lr][c * 32 + lg * 8];
                const size_t vbase = ((size_t)((kb >> 5) + c) * 4) * 512;
                #pragma unroll
                for (int dt = 0; dt < 4; ++dt) {
                    const short8 vbd = *(const short8*)
                        &Vp[vbase + (size_t)dt * 512 + (size_t)l * 8];
                    acc[dt] = __builtin_amdgcn_mfma_f32_16x16x32_bf16(pa, vbd, acc[dt], 0, 0, 0);
                }
            }
        }
        asm volatile("s_waitcnt lgkmcnt(0)" ::: "memory");
    }

    // ---- combine halves (fixed m => partials add directly) ----
    if (half == 1) {
        #pragma unroll
        for (int dt = 0; dt < 4; ++dt) RedAcc[g][l][dt] = acc[dt];
        #pragma unroll
        for (int i = 0; i < 4; ++i) RedSum[g][l][i] = lsum[i];
    }
    __syncthreads();
    if (half == 0) {
        #pragma unroll
        for (int dt = 0; dt < 4; ++dt) acc[dt] += RedAcc[g][l][dt];
        #pragma unroll
        for (int i = 0; i < 4; ++i) lsum[i] += RedSum[g][l][i];

        // reduce lsum over the 16 key-lanes (within the lg group)
        #pragma unroll
        for (int d = 1; d < 16; d <<= 1)
            #pragma unroll
            for (int i = 0; i < 4; ++i) lsum[i] += __shfl_xor(lsum[i], d);

        float inv[4];
        #pragma unroll
        for (int i = 0; i < 4; ++i) inv[i] = 1.0f / lsum[i];

        const size_t orow = (size_t)bx * 1024 + qw0;
        #pragma unroll
        for (int dt = 0; dt < 4; ++dt)
            #pragma unroll
            for (int i = 0; i < 4; ++i)
                out[(orow + lg * 4 + i) * 64 + dt * 16 + lr] = acc[dt][i] * inv[i];
    }
}

extern "C" void kernel_launch(void* const* d_in, const int* in_sizes, int n_in,
                              void* d_out, int out_size, void* d_ws, size_t ws_size,
                              hipStream_t stream) {
    const float* k_in = (const float*)d_in[0];
    const float* v_in = (const float*)d_in[1];
    const float* q_in = (const float*)d_in[2];
    const float* k_w  = (const float*)d_in[3];
    const float* v_w  = (const float*)d_in[4];
    const float* q_w  = (const float*)d_in[5];

    unsigned short* Kb    = (unsigned short*)d_ws;              // [65536][64] bf16
    unsigned short* Vf    = Kb + (size_t)NROWS * 64;            // V fragments, 8 MB
    unsigned short* Qb    = Vf + (size_t)NROWS * 64;            // [65536][64] bf16 (scale in W)
    unsigned short* Wfrag = Qb + (size_t)NROWS * 64;            // 3 x 32768 bf16 fragments

    wprep_kernel<<<dim3(16, 3), 256, 0, stream>>>(k_w, v_w, q_w, Wfrag);
    proj_kernel<<<dim3(512, 3), 512, 0, stream>>>(
        k_in, v_in, q_in, Wfrag, Kb, Vf, Qb);
    attn_kernel<<<dim3(64, 16), 512, 0, stream>>>(Qb, Kb, Vf, (float*)d_out);
}

// Round 20
// 117.376 us; speedup vs baseline: 1.2459x; 1.0951x over previous
//
#include <hip/hip_runtime.h>
#include <hip/hip_bf16.h>

// AttentionHeadRankFour: B=8, X=8, S=1024, D_IN=512, D_OUT=64
// out = softmax_causal( (Xq Wq)(Xk Wk)^T / sqrt(S) ) (Xv Wv)
//
// Pass 0: wprep -> bf16 fragment-ordered W (q_w pre-scaled by log2e/32).
// Pass 1: proj v8 (frozen r19): wave-private A staging, nt loads, barrier-
//         free K-loop; V written in PV-fragment order.
// Pass 2: attn v12 — 2 q-tiles per wave (128 queries/block) over one K/V
//         register stream: halves wave-chunks and K/V L2 traffic, doubles
//         MFMA per byte. 8 waves = (half, g); fixed-m exp2 softmax;
//         half-combine via LDS (fixed m => partials addable).

typedef short  short8 __attribute__((ext_vector_type(8)));
typedef float  f32x4  __attribute__((ext_vector_type(4)));

#define DIN   512
#define DOUT  64
#define SEQ   1024
#define NROWS 65536   // 8*8*1024

__device__ __forceinline__ unsigned short f2bf(float f) {
    unsigned int u = __float_as_uint(f);
    u += 0x7FFF + ((u >> 16) & 1);   // RNE
    return (unsigned short)(u >> 16);
}

__device__ __forceinline__ unsigned short f2bf_rhu(float f) {   // round-half-up (cheap)
    return (unsigned short)((__float_as_uint(f) + 0x8000u) >> 16);
}

__device__ __forceinline__ float fast_exp2(float x) {
    float r;
    asm("v_exp_f32 %0, %1" : "=v"(r) : "v"(x));
    return r;
}

// ---------------------------------------------------------------------------
// Weight prep: grid (16,3), 256 thr. Wfrag[mode][kk][nt][lane][8] bf16,
// element = W[kk*32 + lg*8 + j][nt*16 + lr]; mode 2 pre-scaled by log2e/32.
// ---------------------------------------------------------------------------
__global__ __launch_bounds__(256)
void wprep_kernel(const float* __restrict__ k_w, const float* __restrict__ v_w,
                  const float* __restrict__ q_w, unsigned short* __restrict__ Wfrag)
{
    const int mode = blockIdx.y;
    const float* w = (mode == 0) ? k_w : (mode == 1) ? v_w : q_w;
    const float sc = (mode == 2) ? 0.0450842200277801f : 1.0f;  // log2(e)/32
    unsigned short* outp = Wfrag + (size_t)mode * 32768;

    const int s  = blockIdx.x * 256 + threadIdx.x;   // (kk,nt,lane) slot
    const int l  = s & 63;
    const int nt = (s >> 6) & 3;
    const int kk = s >> 8;
    const int lr = l & 15, lg = l >> 4;
    short8 frag;
    #pragma unroll
    for (int j = 0; j < 8; ++j)
        frag[j] = (short)f2bf(w[(kk * 32 + lg * 8 + j) * 64 + nt * 16 + lr] * sc);
    *(short8*)&outp[(size_t)s * 8] = frag;
}

// ---------------------------------------------------------------------------
// proj v8 (frozen r19). Grid (512, 3), 512 thr = 8 waves. Wave owns 16 rows
// x K=512, stages its own chunks into its own 8 KB LDS dbuf slice. nt loads,
// XOR swizzle, no barriers in the K-loop.
// mode 0: keys -> Kb; mode 2: queries -> Qb; mode 1: values -> Vfrag.
// ---------------------------------------------------------------------------
__global__ __launch_bounds__(512, 2)
void proj_kernel(const float* __restrict__ k_in, const float* __restrict__ v_in,
                 const float* __restrict__ q_in,
                 const unsigned short* __restrict__ Wfrag,
                 unsigned short* __restrict__ Kb, unsigned short* __restrict__ Vf,
                 unsigned short* __restrict__ Qb)
{
    const int mode = blockIdx.y;
    const float* in = (mode == 0) ? k_in : (mode == 1) ? v_in : q_in;
    const unsigned short* wf = Wfrag + (size_t)mode * 32768;

    __shared__ __align__(16) unsigned short Wlds[32768];        // 64 KB
    __shared__ __align__(16) unsigned short Alds[8][2][2048];   // 8 waves x 2 x 4 KB

    const int tid = threadIdx.x;
    const int wid = tid >> 6;
    const int l   = tid & 63;
    const int lr  = l & 15;
    const int lg  = l >> 4;
    const int r0  = blockIdx.x * 128 + wid * 16;   // wave's first row

    const int srow = l >> 5;            // + 2*i
    const int scolb = (l & 31) * 8;     // bf16 byte offset within row
    const float* sbase = in + (size_t)(r0 + srow) * DIN + (l & 31) * 4;

    f32x4 rA[8], rB[8];

    #define LOADC(r, c)                                                        \
        { _Pragma("unroll")                                                    \
          for (int i = 0; i < 8; ++i)                                          \
              r[i] = __builtin_nontemporal_load(                               \
                  (const f32x4*)(sbase + (size_t)(2 * i) * DIN + (c) * 128)); }

    #define WRITEC(buf, r)                                                     \
        { _Pragma("unroll")                                                    \
          for (int i = 0; i < 8; ++i) {                                        \
              const int row = 2 * i + srow;                                    \
              ushort4 pk;                                                      \
              pk.x = f2bf(r[i].x); pk.y = f2bf(r[i].y);                        \
              pk.z = f2bf(r[i].z); pk.w = f2bf(r[i].w);                        \
              *(ushort4*)((char*)&Alds[wid][buf][0] +                          \
                  ((row * 256 + scolb) ^ ((row & 7) << 4))) = pk;              \
          } }

    const int abase = lr * 256 + lg * 16;   // byte offset, + k*64
    const int aswz  = (lr & 7) << 4;

    f32x4 acc[4];
    #pragma unroll
    for (int nt = 0; nt < 4; ++nt)
        #pragma unroll
        for (int i = 0; i < 4; ++i) acc[nt][i] = 0.f;

    #define COMPUTEC(buf, c)                                                   \
        { _Pragma("unroll")                                                    \
          for (int k = 0; k < 4; ++k) {                                        \
              const short8 af = *(const short8*)((const char*)&Alds[wid][buf][0] + \
                                  ((abase + k * 64) ^ aswz));                  \
              const int kk = (c) * 4 + k;                                      \
              _Pragma("unroll")                                                \
              for (int nt = 0; nt < 4; ++nt) {                                 \
                  const short8 bf = *(const short8*)&Wlds[((kk * 4 + nt) * 64 + l) * 8]; \
                  acc[nt] = __builtin_amdgcn_mfma_f32_16x16x32_bf16(af, bf, acc[nt], 0, 0, 0); \
              }                                                                \
          } }

    LOADC(rA, 0);
    LOADC(rB, 1);
    #pragma unroll
    for (int i = 0; i < 8; ++i)
        *(short8*)&Wlds[(i * 512 + tid) * 8] = *(const short8*)&wf[(size_t)(i * 512 + tid) * 8];
    __syncthreads();

    WRITEC(0, rA);
    LOADC(rA, 2);
    COMPUTEC(0, 0);

    WRITEC(1, rB);
    LOADC(rB, 3);
    COMPUTEC(1, 1);

    WRITEC(0, rA);
    COMPUTEC(0, 2);

    WRITEC(1, rB);
    COMPUTEC(1, 3);

    if (mode == 1) {
        const int grow = r0 + lg * 4;
        const int bx = grow >> 10;
        const int sl = grow & 1023;
        const int sg = sl >> 5;
        const int lp = (((sl & 31) >> 3) << 4) | lr;
        const int j0 = sl & 7;
        #pragma unroll
        for (int nt = 0; nt < 4; ++nt) {
            ushort4 pk;
            pk.x = f2bf(acc[nt][0]); pk.y = f2bf(acc[nt][1]);
            pk.z = f2bf(acc[nt][2]); pk.w = f2bf(acc[nt][3]);
            *(ushort4*)&Vf[(((size_t)bx * 32 + sg) * 4 + nt) * 512 + (size_t)lp * 8 + j0] = pk;
        }
    } else {
        unsigned short* outp = (mode == 0) ? Kb : Qb;
        const int rbase = r0 + lg * 4;
        #pragma unroll
        for (int nt = 0; nt < 4; ++nt)
            #pragma unroll
            for (int i = 0; i < 4; ++i)
                outp[(size_t)(rbase + i) * 64 + nt * 16 + lr] = f2bf(acc[nt][i]);
    }
    #undef LOADC
    #undef WRITEC
    #undef COMPUTEC
}

// ---------------------------------------------------------------------------
// attn v12. Grid (64 bx, 8 qs), 512 thr = 8 waves: wave = (half, g).
// Block owns 128 queries (qs*128..+127); wave g handles TWO q-tiles:
// q0 = qs*128 + g*16 (low), q1 = q0 + 64 (high), sharing one K/V register
// stream. half = interleaved key-half (kb = half*64, step 128).
// Chunk: KVBLK=64, mfma(Q,K) per tile (C: col=lr=key, row=lg*4+i=query),
// fixed-m softmax p = 2^(s-8), lane-local lsum per tile; PV from Vfrag
// (1 KB contiguous per wave instr), V regs reused by both q-tiles.
// Halves combine via LDS add (fixed m => partials addable).
// ---------------------------------------------------------------------------
__global__ __launch_bounds__(512)
void attn_kernel(const unsigned short* __restrict__ Qb,
                 const unsigned short* __restrict__ Kb,
                 const unsigned short* __restrict__ Vf,
                 float* __restrict__ out)
{
    __shared__ __align__(16) unsigned short Plds[8][2][16][72];  // [wave][qt][q][key]
    __shared__ __align__(16) f32x4 RedAcc[4][2][64][4];          // [g][qt][lane][dt] 32 KB
    __shared__ float RedSum[4][2][64][4];                        // [g][qt][lane][i]   8 KB

    const int tid  = threadIdx.x;
    const int wid  = tid >> 6;
    const int g    = wid & 3;
    const int half = wid >> 2;
    const int l    = tid & 63;
    const int lr   = l & 15;
    const int lg   = l >> 4;
    const int bx   = blockIdx.x;
    const int qs   = 7 - (int)blockIdx.y;        // big blocks first
    const int q0   = qs * 128 + g * 16;
    const int q1   = q0 + 64;

    const unsigned short* Qp = Qb + (size_t)bx * 65536;
    const unsigned short* Kp = Kb + (size_t)bx * 65536;
    const unsigned short* Vp = Vf + (size_t)bx * 65536;   // fragment order

    const short8 qa0 = *(const short8*)&Qp[(size_t)(q0 + lr) * 64 + lg * 8];
    const short8 qa1 = *(const short8*)&Qp[(size_t)(q0 + lr) * 64 + 32 + lg * 8];
    const short8 qb0 = *(const short8*)&Qp[(size_t)(q1 + lr) * 64 + lg * 8];
    const short8 qb1 = *(const short8*)&Qp[(size_t)(q1 + lr) * 64 + 32 + lg * 8];

    const int qrow0 = q0 + lg * 4;   // + i
    const int qrow1 = q1 + lg * 4;   // + i

    float lsum0[4] = {0.f, 0.f, 0.f, 0.f};
    float lsum1[4] = {0.f, 0.f, 0.f, 0.f};
    f32x4 acc0[4], acc1[4];
    #pragma unroll
    for (int dt = 0; dt < 4; ++dt)
        #pragma unroll
        for (int i = 0; i < 4; ++i) { acc0[dt][i] = 0.f; acc1[dt][i] = 0.f; }

    for (int kb = half * 64; kb <= q1; kb += 128) {
        // ---- scores -> p -> LDS: 4 tiles of 16 keys, both q-tiles ----
        #pragma unroll
        for (int kt = 0; kt < 4; ++kt) {
            const int kbase = kb + kt * 16;
            if (kbase <= q1) {                 // wave-uniform
                const short8 k0 = *(const short8*)&Kp[(size_t)(kbase + lr) * 64 + lg * 8];
                const short8 k1 = *(const short8*)&Kp[(size_t)(kbase + lr) * 64 + 32 + lg * 8];
                // high q-tile (q1): always active here
                f32x4 t;
                #pragma unroll
                for (int i = 0; i < 4; ++i) t[i] = 0.f;
                t = __builtin_amdgcn_mfma_f32_16x16x32_bf16(qb0, k0, t, 0, 0, 0);
                t = __builtin_amdgcn_mfma_f32_16x16x32_bf16(qb1, k1, t, 0, 0, 0);
                const int kcol = kbase + lr;
                #pragma unroll
                for (int i = 0; i < 4; ++i) {
                    const float p = (kcol <= qrow1 + i) ? fast_exp2(t[i] - 8.0f) : 0.f;
                    lsum1[i] += p;
                    Plds[wid][1][lg * 4 + i][kt * 16 + lr] = f2bf_rhu(p);
                }
                // low q-tile (q0)
                if (kbase <= q0) {             // wave-uniform
                    f32x4 u;
                    #pragma unroll
                    for (int i = 0; i < 4; ++i) u[i] = 0.f;
                    u = __builtin_amdgcn_mfma_f32_16x16x32_bf16(qa0, k0, u, 0, 0, 0);
                    u = __builtin_amdgcn_mfma_f32_16x16x32_bf16(qa1, k1, u, 0, 0, 0);
                    #pragma unroll
                    for (int i = 0; i < 4; ++i) {
                        const float p = (kcol <= qrow0 + i) ? fast_exp2(u[i] - 8.0f) : 0.f;
                        lsum0[i] += p;
                        Plds[wid][0][lg * 4 + i][kt * 16 + lr] = f2bf_rhu(p);
                    }
                } else {
                    #pragma unroll
                    for (int i = 0; i < 4; ++i)
                        Plds[wid][0][lg * 4 + i][kt * 16 + lr] = 0;
                }
            } else {
                #pragma unroll
                for (int i = 0; i < 4; ++i) {
                    Plds[wid][0][lg * 4 + i][kt * 16 + lr] = 0;
                    Plds[wid][1][lg * 4 + i][kt * 16 + lr] = 0;
                }
            }
        }

        // wave-private LDS write -> read (same wave)
        asm volatile("s_waitcnt lgkmcnt(0)" ::: "memory");
        __builtin_amdgcn_sched_barrier(0);

        // ---- PV: 2 groups of 32 keys; V regs shared by both q-tiles ----
        #pragma unroll
        for (int c = 0; c < 2; ++c) {
            if (kb + c * 32 <= q1 + 15) {      // wave-uniform
                const size_t vbase = ((size_t)((kb >> 5) + c) * 4) * 512;
                short8 vv[4];
                #pragma unroll
                for (int dt = 0; dt < 4; ++dt)
                    vv[dt] = *(const short8*)&Vp[vbase + (size_t)dt * 512 + (size_t)l * 8];
                const short8 pa1 = *(const short8*)&Plds[wid][1][lr][c * 32 + lg * 8];
                #pragma unroll
                for (int dt = 0; dt < 4; ++dt)
                    acc1[dt] = __builtin_amdgcn_mfma_f32_16x16x32_bf16(pa1, vv[dt], acc1[dt], 0, 0, 0);
                if (kb + c * 32 <= q0 + 15) {  // wave-uniform
                    const short8 pa0 = *(const short8*)&Plds[wid][0][lr][c * 32 + lg * 8];
                    #pragma unroll
                    for (int dt = 0; dt < 4; ++dt)
                        acc0[dt] = __builtin_amdgcn_mfma_f32_16x16x32_bf16(pa0, vv[dt], acc0[dt], 0, 0, 0);
                }
            }
        }
        asm volatile("s_waitcnt lgkmcnt(0)" ::: "memory");
    }

    // ---- combine halves (fixed m => partials add directly) ----
    if (half == 1) {
        #pragma unroll
        for (int dt = 0; dt < 4; ++dt) {
            RedAcc[g][0][l][dt] = acc0[dt];
            RedAcc[g][1][l][dt] = acc1[dt];
        }
        #pragma unroll
        for (int i = 0; i < 4; ++i) {
            RedSum[g][0][l][i] = lsum0[i];
            RedSum[g][1][l][i] = lsum1[i];
        }
    }
    __syncthreads();
    if (half == 0) {
        #pragma unroll
        for (int dt = 0; dt < 4; ++dt) {
            acc0[dt] += RedAcc[g][0][l][dt];
            acc1[dt] += RedAcc[g][1][l][dt];
        }
        #pragma unroll
        for (int i = 0; i < 4; ++i) {
            lsum0[i] += RedSum[g][0][l][i];
            lsum1[i] += RedSum[g][1][l][i];
        }

        // reduce lsum over the 16 key-lanes (within the lg group)
        #pragma unroll
        for (int d = 1; d < 16; d <<= 1)
            #pragma unroll
            for (int i = 0; i < 4; ++i) {
                lsum0[i] += __shfl_xor(lsum0[i], d);
                lsum1[i] += __shfl_xor(lsum1[i], d);
            }

        float inv0[4], inv1[4];
        #pragma unroll
        for (int i = 0; i < 4; ++i) {
            inv0[i] = 1.0f / lsum0[i];
            inv1[i] = 1.0f / lsum1[i];
        }

        const size_t orow0 = (size_t)bx * 1024 + q0;
        const size_t orow1 = (size_t)bx * 1024 + q1;
        #pragma unroll
        for (int dt = 0; dt < 4; ++dt)
            #pragma unroll
            for (int i = 0; i < 4; ++i) {
                out[(orow0 + lg * 4 + i) * 64 + dt * 16 + lr] = acc0[dt][i] * inv0[i];
                out[(orow1 + lg * 4 + i) * 64 + dt * 16 + lr] = acc1[dt][i] * inv1[i];
            }
    }
}

extern "C" void kernel_launch(void* const* d_in, const int* in_sizes, int n_in,
                              void* d_out, int out_size, void* d_ws, size_t ws_size,
                              hipStream_t stream) {
    const float* k_in = (const float*)d_in[0];
    const float* v_in = (const float*)d_in[1];
    const float* q_in = (const float*)d_in[2];
    const float* k_w  = (const float*)d_in[3];
    const float* v_w  = (const float*)d_in[4];
    const float* q_w  = (const float*)d_in[5];

    unsigned short* Kb    = (unsigned short*)d_ws;              // [65536][64] bf16
    unsigned short* Vf    = Kb + (size_t)NROWS * 64;            // V fragments, 8 MB
    unsigned short* Qb    = Vf + (size_t)NROWS * 64;            // [65536][64] bf16 (scale in W)
    unsigned short* Wfrag = Qb + (size_t)NROWS * 64;            // 3 x 32768 bf16 fragments

    wprep_kernel<<<dim3(16, 3), 256, 0, stream>>>(k_w, v_w, q_w, Wfrag);
    proj_kernel<<<dim3(512, 3), 512, 0, stream>>>(
        k_in, v_in, q_in, Wfrag, Kb, Vf, Qb);
    attn_kernel<<<dim3(64, 8), 512, 0, stream>>>(Qb, Kb, Vf, (float*)d_out);
}